// Round 7
// baseline (273.609 us; speedup 1.0000x reference)
//
#include <hip/hip_runtime.h>
#include <hip/hip_bf16.h>
#include <stdint.h>

#define N_BATCH 4096
#define D_DIM   1024
#define M_ROWS  8192                     // 2N
#define TINV    2.0f                     // 1/temperature
#define EXP_SCALE 2.8853900817779268f    // log2(e)/t  (t=0.5)
#define LN2 0.6931471805599453f
#define NBLOCKS 2080                     // 64*65/2 triangular 128x128 tiles

typedef float f32x4 __attribute__((ext_vector_type(4)));

__device__ __forceinline__ void load_lds16(const void* g, void* l) {
    __builtin_amdgcn_global_load_lds(
        (const __attribute__((address_space(1))) void*)g,
        (__attribute__((address_space(3))) void*)l, 16, 0, 0);
}
// s_waitcnt with vmcnt(n), expcnt/lgkmcnt unconstrained (0xF70 = exp7|lgkm15)
#define WAIT_VM(n) do { \
    __asm__ volatile("" ::: "memory"); \
    __builtin_amdgcn_s_waitcnt(0xF70 | (n)); \
    __asm__ volatile("" ::: "memory"); } while (0)

// ---- kernel 1: L2-normalize -> fp8 e4m3 Z (8 MB) + exact fp32 positives --
__global__ __launch_bounds__(256) void norm_pos_kernel(
    const float* __restrict__ emb_i, const float* __restrict__ emb_j,
    uint8_t* __restrict__ zq, float* __restrict__ pos,
    float* __restrict__ denom, unsigned* __restrict__ counter)
{
    int i = blockIdx.x;
    int t = threadIdx.x;
    float4 va = ((const float4*)(emb_i + (size_t)i * D_DIM))[t];
    float4 vb = ((const float4*)(emb_j + (size_t)i * D_DIM))[t];
    float ssa = va.x*va.x + va.y*va.y + va.z*va.z + va.w*va.w;
    float ssb = vb.x*vb.x + vb.y*vb.y + vb.z*vb.z + vb.w*vb.w;
    float dot = va.x*vb.x + va.y*vb.y + va.z*vb.z + va.w*vb.w;
    #pragma unroll
    for (int m = 1; m < 64; m <<= 1) {
        ssa += __shfl_xor(ssa, m, 64);
        ssb += __shfl_xor(ssb, m, 64);
        dot += __shfl_xor(dot, m, 64);
    }
    __shared__ float ra[4], rb[4], rd[4];
    int wv = t >> 6;
    if ((t & 63) == 0) { ra[wv] = ssa; rb[wv] = ssb; rd[wv] = dot; }
    __syncthreads();
    float SSA = ra[0] + ra[1] + ra[2] + ra[3];
    float SSB = rb[0] + rb[1] + rb[2] + rb[3];
    float na = fmaxf(sqrtf(SSA), 1e-12f);
    float nb = fmaxf(sqrtf(SSB), 1e-12f);
    float sa = 1.0f / na, sb = 1.0f / nb;
    // pack 4 floats -> 4 fp8 e4m3 (OCP, RNE) bytes
    int pk = __builtin_amdgcn_cvt_pk_fp8_f32(va.x * sa, va.y * sa, 0, false);
    pk     = __builtin_amdgcn_cvt_pk_fp8_f32(va.z * sa, va.w * sa, pk, true);
    ((int*)(zq + (size_t)i * D_DIM))[t] = pk;
    pk = __builtin_amdgcn_cvt_pk_fp8_f32(vb.x * sb, vb.y * sb, 0, false);
    pk = __builtin_amdgcn_cvt_pk_fp8_f32(vb.z * sb, vb.w * sb, pk, true);
    ((int*)(zq + (size_t)(i + N_BATCH) * D_DIM))[t] = pk;
    if (t == 0) {
        float DOT = rd[0] + rd[1] + rd[2] + rd[3];
        pos[i] = DOT / (na * nb);
        denom[i] = 0.0f;
        denom[i + N_BATCH] = 0.0f;
        if (i == 0) *counter = 0u;
    }
}

// ---- kernel 2: sim = Z Z^T (fp8 MFMA) -> exp -> masked sums -> loss ------
// BARRIER-FREE K-loop, wave-private LDS staging, EXPLICIT vmcnt pipelining:
// each iter issues 4 DMAs for it+1 then waits vmcnt(4) (= previous iter's
// DMAs done, new ones still in flight -- never drains to 0 mid-loop).
// R6's NaN root cause: compiler does NOT emit waits between global_load_lds
// and ds_read of other offsets in the same buffer (alias width = 16B only);
// waits must be explicit. 32 KB LDS/block, 4 blocks/CU, supertile swizzle.
__global__ __launch_bounds__(256, 4) void simexp_kernel(
    const uint8_t* __restrict__ Z, float* __restrict__ denom,
    const float* __restrict__ pos, unsigned* __restrict__ counter,
    float* __restrict__ out)
{
    // ---- supertile decode: superrow sy has 36 + (7-sy)*64 blocks ----
    int bid = blockIdx.x;
    int sy = 0;
    for (;;) { int c = 36 + (7 - sy) * 64; if (bid < c) break; bid -= c; sy++; }
    int by, bx;
    if (bid < 36) {                       // diagonal supertile (8x8 triangle)
        int iy = 0, rem = bid;
        while (rem >= 8 - iy) { rem -= 8 - iy; iy++; }
        by = sy * 8 + iy; bx = by + rem;
    } else {
        int r2 = bid - 36;
        int sx = sy + 1 + (r2 >> 6);
        int w  = r2 & 63;
        by = sy * 8 + (w >> 3);
        bx = sx * 8 + (w & 7);
    }
    int tile_m = by * 128, tile_n = bx * 128;

    // [wave][buf][A=0/B=1][2048 B]  -> 32 KB total, wave-private regions
    __shared__ __align__(16) uint8_t sh[4][2][2][2048];

    int t    = threadIdx.x;
    int wv   = t >> 6;
    int lane = t & 63;
    int wave_m = (wv >> 1) * 64;
    int wave_n = (wv & 1) * 64;
    int quad = lane >> 4;
    int l15  = lane & 15;

    // DMA source: lane -> row lane/2 (+32 for 2nd instr), 16B half (lane&1)
    const uint8_t* gA = Z + (size_t)(tile_m + wave_m + (lane >> 1)) * D_DIM
                          + (lane & 1) * 16;
    const uint8_t* gB = Z + (size_t)(tile_n + wave_n + (lane >> 1)) * D_DIM
                          + (lane & 1) * 16;

    f32x4 acc[4][4] = {};

    // prologue: stage k-chunk 0 into buf 0 (wave-local, no barrier)
    load_lds16(gA,              &sh[wv][0][0][0]);
    load_lds16(gA + 32 * D_DIM, &sh[wv][0][0][1024]);
    load_lds16(gB,              &sh[wv][0][1][0]);
    load_lds16(gB + 32 * D_DIM, &sh[wv][0][1][1024]);

    for (int it = 0; it < 32; ++it) {
        int p = it & 1;
        if (it + 1 < 32) {
            int k0 = (it + 1) * 32;       // 32 fp8 = 32 B per k-chunk
            load_lds16(gA + k0,              &sh[wv][p ^ 1][0][0]);
            load_lds16(gA + 32 * D_DIM + k0, &sh[wv][p ^ 1][0][1024]);
            load_lds16(gB + k0,              &sh[wv][p ^ 1][1][0]);
            load_lds16(gB + 32 * D_DIM + k0, &sh[wv][p ^ 1][1][1024]);
            WAIT_VM(4);   // previous iter's 4 DMAs (buf p) landed; 4 in flight
        } else {
            WAIT_VM(0);   // last iter: drain the 4 for buf p
        }
        // fragments: row-major 64 rows x 32 B chunk; A[row=f*16+l15][k=quad*8..+8]
        long af[4], bf[4];
        #pragma unroll
        for (int f = 0; f < 4; ++f) {
            af[f] = *(const long*)&sh[wv][p][0][(f * 16 + l15) * 32 + quad * 8];
            bf[f] = *(const long*)&sh[wv][p][1][(f * 16 + l15) * 32 + quad * 8];
        }
        #pragma unroll
        for (int fm = 0; fm < 4; ++fm)
            #pragma unroll
            for (int fn = 0; fn < 4; ++fn)
                acc[fm][fn] = __builtin_amdgcn_mfma_f32_16x16x32_fp8_fp8(
                    af[fm], bf[fn], acc[fm][fn], 0, 0, 0);
    }

    // epilogue: e = exp2(sim*log2(e)/t) only where c>r; row + col reductions
    int rbase = tile_m + wave_m + quad * 4;
    int cbase = tile_n + wave_n + l15;
    float colacc[4] = {0.f, 0.f, 0.f, 0.f};
    #pragma unroll
    for (int fm = 0; fm < 4; ++fm) {
        #pragma unroll
        for (int r = 0; r < 4; ++r) {
            int rg = rbase + fm * 16 + r;
            float rowacc = 0.f;
            #pragma unroll
            for (int fn = 0; fn < 4; ++fn) {
                int cg = cbase + fn * 16;
                float e = (cg > rg)
                    ? __builtin_amdgcn_exp2f(acc[fm][fn][r] * EXP_SCALE)
                    : 0.f;
                rowacc += e;
                colacc[fn] += e;
            }
            rowacc += __shfl_xor(rowacc, 1, 64);
            rowacc += __shfl_xor(rowacc, 2, 64);
            rowacc += __shfl_xor(rowacc, 4, 64);
            rowacc += __shfl_xor(rowacc, 8, 64);
            if (l15 == 0) atomicAdd(&denom[rg], rowacc);
        }
    }
    #pragma unroll
    for (int fn = 0; fn < 4; ++fn) {
        float s = colacc[fn];
        s += __shfl_xor(s, 16, 64);
        s += __shfl_xor(s, 32, 64);
        if (quad == 0) atomicAdd(&denom[cbase + fn * 16], s);
    }

    // ---- last block computes the loss ----
    __shared__ bool amLast;
    __syncthreads();
    if (t == 0) {
        __threadfence();                            // denom atomics visible
        amLast = (atomicAdd(counter, 1u) == NBLOCKS - 1);
    }
    __syncthreads();
    if (!amLast) return;

    float a1 = 0.f, a2 = 0.f;
    for (int r = t; r < M_ROWS; r += 256) {
        float d = __hip_atomic_load(&denom[r], __ATOMIC_RELAXED,
                                    __HIP_MEMORY_SCOPE_AGENT);
        a1 += __builtin_amdgcn_logf(d) * LN2;       // v_log_f32 is log2
    }
    for (int i = t; i < N_BATCH; i += 256)
        a2 += pos[i];
    #pragma unroll
    for (int m = 1; m < 64; m <<= 1) {
        a1 += __shfl_xor(a1, m, 64);
        a2 += __shfl_xor(a2, m, 64);
    }
    __shared__ float r1[4], r2[4];
    if ((t & 63) == 0) { r1[t >> 6] = a1; r2[t >> 6] = a2; }
    __syncthreads();
    if (t == 0) {
        float s1 = r1[0] + r1[1] + r1[2] + r1[3];
        float s2 = r2[0] + r2[1] + r2[2] + r2[3];
        out[0] = (s1 - 2.0f * TINV * s2) / (float)M_ROWS;
    }
}

extern "C" void kernel_launch(void* const* d_in, const int* in_sizes, int n_in,
                              void* d_out, int out_size, void* d_ws, size_t ws_size,
                              hipStream_t stream)
{
    const float* emb_i = (const float*)d_in[0];
    const float* emb_j = (const float*)d_in[1];
    float* out = (float*)d_out;

    char*     ws      = (char*)d_ws;
    uint8_t*  zq      = (uint8_t*)ws;                              // 8 MB fp8
    float*    denom   = (float*)(ws + (size_t)M_ROWS * D_DIM);     // 32 KB
    float*    pos     = denom + M_ROWS;                            // 16 KB
    unsigned* counter = (unsigned*)(pos + N_BATCH);

    hipLaunchKernelGGL(norm_pos_kernel, dim3(N_BATCH), dim3(256), 0, stream,
                       emb_i, emb_j, zq, pos, denom, counter);
    hipLaunchKernelGGL(simexp_kernel, dim3(NBLOCKS), dim3(256), 0, stream,
                       zq, denom, pos, counter, out);
}

// Round 8
// 259.332 us; speedup vs baseline: 1.0551x; 1.0551x over previous
//
#include <hip/hip_runtime.h>
#include <hip/hip_bf16.h>
#include <stdint.h>

#define N_BATCH 4096
#define D_DIM   1024
#define M_ROWS  8192                     // 2N
#define TINV    2.0f                     // 1/temperature
#define EXP_SCALE 2.8853900817779268f    // log2(e)/t  (t=0.5)
#define LN2 0.6931471805599453f
#define NBLOCKS 2080                     // 64*65/2 triangular 128x128 tiles

typedef float f32x4 __attribute__((ext_vector_type(4)));

__device__ __forceinline__ void load_lds16(const void* g, void* l) {
    __builtin_amdgcn_global_load_lds(
        (const __attribute__((address_space(1))) void*)g,
        (__attribute__((address_space(3))) void*)l, 16, 0, 0);
}
// s_waitcnt with vmcnt(n), expcnt/lgkmcnt unconstrained (0xF70 = exp7|lgkm15)
#define WAIT_VM(n) do { \
    __asm__ volatile("" ::: "memory"); \
    __builtin_amdgcn_s_waitcnt(0xF70 | (n)); \
    __asm__ volatile("" ::: "memory"); } while (0)

// ---- kernel 1: L2-normalize -> fp8 e4m3 Z (8 MB) + exact fp32 positives --
__global__ __launch_bounds__(256) void norm_pos_kernel(
    const float* __restrict__ emb_i, const float* __restrict__ emb_j,
    uint8_t* __restrict__ zq, float* __restrict__ pos,
    float* __restrict__ denom, unsigned* __restrict__ counter)
{
    int i = blockIdx.x;
    int t = threadIdx.x;
    float4 va = ((const float4*)(emb_i + (size_t)i * D_DIM))[t];
    float4 vb = ((const float4*)(emb_j + (size_t)i * D_DIM))[t];
    float ssa = va.x*va.x + va.y*va.y + va.z*va.z + va.w*va.w;
    float ssb = vb.x*vb.x + vb.y*vb.y + vb.z*vb.z + vb.w*vb.w;
    float dot = va.x*vb.x + va.y*vb.y + va.z*vb.z + va.w*vb.w;
    #pragma unroll
    for (int m = 1; m < 64; m <<= 1) {
        ssa += __shfl_xor(ssa, m, 64);
        ssb += __shfl_xor(ssb, m, 64);
        dot += __shfl_xor(dot, m, 64);
    }
    __shared__ float ra[4], rb[4], rd[4];
    int wv = t >> 6;
    if ((t & 63) == 0) { ra[wv] = ssa; rb[wv] = ssb; rd[wv] = dot; }
    __syncthreads();
    float SSA = ra[0] + ra[1] + ra[2] + ra[3];
    float SSB = rb[0] + rb[1] + rb[2] + rb[3];
    float na = fmaxf(sqrtf(SSA), 1e-12f);
    float nb = fmaxf(sqrtf(SSB), 1e-12f);
    float sa = 1.0f / na, sb = 1.0f / nb;
    // pack 4 floats -> 4 fp8 e4m3 (OCP, RNE) bytes
    int pk = __builtin_amdgcn_cvt_pk_fp8_f32(va.x * sa, va.y * sa, 0, false);
    pk     = __builtin_amdgcn_cvt_pk_fp8_f32(va.z * sa, va.w * sa, pk, true);
    ((int*)(zq + (size_t)i * D_DIM))[t] = pk;
    pk = __builtin_amdgcn_cvt_pk_fp8_f32(vb.x * sb, vb.y * sb, 0, false);
    pk = __builtin_amdgcn_cvt_pk_fp8_f32(vb.z * sb, vb.w * sb, pk, true);
    ((int*)(zq + (size_t)(i + N_BATCH) * D_DIM))[t] = pk;
    if (t == 0) {
        float DOT = rd[0] + rd[1] + rd[2] + rd[3];
        pos[i] = DOT / (na * nb);
        denom[i] = 0.0f;
        denom[i + N_BATCH] = 0.0f;
        if (i == 0) *counter = 0u;
    }
}

// ---- kernel 2: sim = Z Z^T (fp8 MFMA) -> exp -> masked sums -> loss ------
// Barrier-free K-loop, wave-private LDS staging, explicit vmcnt pipelining,
// prefetch depth 2 (3 buffers/wave, steady-state vmcnt(8), never 0).
// Bank-conflict fix (R7: 12 extra cyc per b64 read from 32B row stride):
// k-half swizzle -- DMA sources global half (lane&1)^((lane>>3)&1) so that
// reads at r*32 + ((q>>1)^((r>>2)&1))*16 + (q&1)*8 split the 4-way lane
// collision {l15, l15+4, l15+8, l15+12} into 2x 2-way (free per m136).
// 48 KB LDS/block, 3 blocks/CU, supertile-swizzled triangular grid.
__global__ __launch_bounds__(256, 3) void simexp_kernel(
    const uint8_t* __restrict__ Z, float* __restrict__ denom,
    const float* __restrict__ pos, unsigned* __restrict__ counter,
    float* __restrict__ out)
{
    // ---- supertile decode: superrow sy has 36 + (7-sy)*64 blocks ----
    int bid = blockIdx.x;
    int sy = 0;
    for (;;) { int c = 36 + (7 - sy) * 64; if (bid < c) break; bid -= c; sy++; }
    int by, bx;
    if (bid < 36) {                       // diagonal supertile (8x8 triangle)
        int iy = 0, rem = bid;
        while (rem >= 8 - iy) { rem -= 8 - iy; iy++; }
        by = sy * 8 + iy; bx = by + rem;
    } else {
        int r2 = bid - 36;
        int sx = sy + 1 + (r2 >> 6);
        int w  = r2 & 63;
        by = sy * 8 + (w >> 3);
        bx = sx * 8 + (w & 7);
    }
    int tile_m = by * 128, tile_n = bx * 128;

    // [wave][buf 0..2][A=0/B=1][2048 B] -> 48 KB, wave-private regions
    __shared__ __align__(16) uint8_t sh[4][3][2][2048];

    int t    = threadIdx.x;
    int wv   = t >> 6;
    int lane = t & 63;
    int wave_m = (wv >> 1) * 64;
    int wave_n = (wv & 1) * 64;
    int quad = lane >> 4;
    int l15  = lane & 15;

    // DMA source: lane -> row lane/2 (+32 for 2nd instr),
    // k-half SWIZZLED: (lane&1) ^ ((lane>>3)&1)  [= (row>>2)&1]
    int khalf = ((lane & 1) ^ ((lane >> 3) & 1)) * 16;
    const uint8_t* gA = Z + (size_t)(tile_m + wave_m + (lane >> 1)) * D_DIM + khalf;
    const uint8_t* gB = Z + (size_t)(tile_n + wave_n + (lane >> 1)) * D_DIM + khalf;

    // fragment LDS byte offsets (per-lane constants): row r=f*16+l15, octet q=quad
    // offset = r*32 + ((q>>1)^((r>>2)&1))*16 + (q&1)*8
    int foff[4];
    #pragma unroll
    for (int f = 0; f < 4; ++f) {
        int r = f * 16 + l15;
        foff[f] = r * 32 + (((quad >> 1) ^ ((r >> 2) & 1)) * 16) + (quad & 1) * 8;
    }

    f32x4 acc[4][4] = {};

    // prologue: stage k-chunks 0,1 into bufs 0,1 (wave-local, no barrier)
    load_lds16(gA,                 &sh[wv][0][0][0]);
    load_lds16(gA + 32 * D_DIM,    &sh[wv][0][0][1024]);
    load_lds16(gB,                 &sh[wv][0][1][0]);
    load_lds16(gB + 32 * D_DIM,    &sh[wv][0][1][1024]);
    load_lds16(gA + 32,            &sh[wv][1][0][0]);
    load_lds16(gA + 32 * D_DIM + 32, &sh[wv][1][0][1024]);
    load_lds16(gB + 32,            &sh[wv][1][1][0]);
    load_lds16(gB + 32 * D_DIM + 32, &sh[wv][1][1][1024]);

    int p = 0;          // buffer holding chunk `it`
    int pw = 2;         // buffer to write chunk `it+2`
    for (int it = 0; it < 32; ++it) {
        if (it + 2 < 32) {
            int k0 = (it + 2) * 32;       // 32 fp8 = 32 B per k-chunk
            load_lds16(gA + k0,              &sh[wv][pw][0][0]);
            load_lds16(gA + 32 * D_DIM + k0, &sh[wv][pw][0][1024]);
            load_lds16(gB + k0,              &sh[wv][pw][1][0]);
            load_lds16(gB + 32 * D_DIM + k0, &sh[wv][pw][1][1024]);
            WAIT_VM(8);   // chunks it+1, it+2 in flight; chunk it landed
        } else if (it == 30) {
            WAIT_VM(4);   // chunk 31 in flight; chunk 30 landed
        } else if (it == 31) {
            WAIT_VM(0);
        }
        long af[4], bf[4];
        #pragma unroll
        for (int f = 0; f < 4; ++f) {
            af[f] = *(const long*)&sh[wv][p][0][foff[f]];
            bf[f] = *(const long*)&sh[wv][p][1][foff[f]];
        }
        #pragma unroll
        for (int fm = 0; fm < 4; ++fm)
            #pragma unroll
            for (int fn = 0; fn < 4; ++fn)
                acc[fm][fn] = __builtin_amdgcn_mfma_f32_16x16x32_fp8_fp8(
                    af[fm], bf[fn], acc[fm][fn], 0, 0, 0);
        p  = (p  == 2) ? 0 : p  + 1;
        pw = (pw == 2) ? 0 : pw + 1;
    }

    // epilogue: e = exp2(sim*log2(e)/t) only where c>r; row + col reductions
    int rbase = tile_m + wave_m + quad * 4;
    int cbase = tile_n + wave_n + l15;
    float colacc[4] = {0.f, 0.f, 0.f, 0.f};
    #pragma unroll
    for (int fm = 0; fm < 4; ++fm) {
        #pragma unroll
        for (int r = 0; r < 4; ++r) {
            int rg = rbase + fm * 16 + r;
            float rowacc = 0.f;
            #pragma unroll
            for (int fn = 0; fn < 4; ++fn) {
                int cg = cbase + fn * 16;
                float e = (cg > rg)
                    ? __builtin_amdgcn_exp2f(acc[fm][fn][r] * EXP_SCALE)
                    : 0.f;
                rowacc += e;
                colacc[fn] += e;
            }
            rowacc += __shfl_xor(rowacc, 1, 64);
            rowacc += __shfl_xor(rowacc, 2, 64);
            rowacc += __shfl_xor(rowacc, 4, 64);
            rowacc += __shfl_xor(rowacc, 8, 64);
            if (l15 == 0) atomicAdd(&denom[rg], rowacc);
        }
    }
    #pragma unroll
    for (int fn = 0; fn < 4; ++fn) {
        float s = colacc[fn];
        s += __shfl_xor(s, 16, 64);
        s += __shfl_xor(s, 32, 64);
        if (quad == 0) atomicAdd(&denom[cbase + fn * 16], s);
    }

    // ---- last block computes the loss ----
    __shared__ bool amLast;
    __syncthreads();
    if (t == 0) {
        __threadfence();                            // denom atomics visible
        amLast = (atomicAdd(counter, 1u) == NBLOCKS - 1);
    }
    __syncthreads();
    if (!amLast) return;

    float a1 = 0.f, a2 = 0.f;
    for (int r = t; r < M_ROWS; r += 256) {
        float d = __hip_atomic_load(&denom[r], __ATOMIC_RELAXED,
                                    __HIP_MEMORY_SCOPE_AGENT);
        a1 += __builtin_amdgcn_logf(d) * LN2;       // v_log_f32 is log2
    }
    for (int i = t; i < N_BATCH; i += 256)
        a2 += pos[i];
    #pragma unroll
    for (int m = 1; m < 64; m <<= 1) {
        a1 += __shfl_xor(a1, m, 64);
        a2 += __shfl_xor(a2, m, 64);
    }
    __shared__ float r1[4], r2[4];
    if ((t & 63) == 0) { r1[t >> 6] = a1; r2[t >> 6] = a2; }
    __syncthreads();
    if (t == 0) {
        float s1 = r1[0] + r1[1] + r1[2] + r1[3];
        float s2 = r2[0] + r2[1] + r2[2] + r2[3];
        out[0] = (s1 - 2.0f * TINV * s2) / (float)M_ROWS;
    }
}

extern "C" void kernel_launch(void* const* d_in, const int* in_sizes, int n_in,
                              void* d_out, int out_size, void* d_ws, size_t ws_size,
                              hipStream_t stream)
{
    const float* emb_i = (const float*)d_in[0];
    const float* emb_j = (const float*)d_in[1];
    float* out = (float*)d_out;

    char*     ws      = (char*)d_ws;
    uint8_t*  zq      = (uint8_t*)ws;                              // 8 MB fp8
    float*    denom   = (float*)(ws + (size_t)M_ROWS * D_DIM);     // 32 KB
    float*    pos     = denom + M_ROWS;                            // 16 KB
    unsigned* counter = (unsigned*)(pos + N_BATCH);

    hipLaunchKernelGGL(norm_pos_kernel, dim3(N_BATCH), dim3(256), 0, stream,
                       emb_i, emb_j, zq, pos, denom, counter);
    hipLaunchKernelGGL(simexp_kernel, dim3(NBLOCKS), dim3(256), 0, stream,
                       zq, denom, pos, counter, out);
}